// Round 7
// baseline (1584.824 us; speedup 1.0000x reference)
//
#include <hip/hip_runtime.h>
#include <math.h>

#define Bx   8
#define Nx   5000
#define Kx   16
#define DINx 128
#define Hx   128
#define G4x  512
#define Mx   40000

typedef __attribute__((ext_vector_type(8))) short sh8;   // 8 bf16 (4 VGPR)
typedef __attribute__((ext_vector_type(4))) float f32x4; // MFMA acc

__device__ __forceinline__ float sigf(float v) {
    return __fdividef(1.0f, 1.0f + __expf(-v));
}
__device__ __forceinline__ float tanf_(float v) {
    return 1.0f - __fdividef(2.0f, __expf(2.0f * v) + 1.0f);
}
__device__ __forceinline__ unsigned short rne16(float f) {
    unsigned int u = __float_as_uint(f);
    return (unsigned short)((u + 0x7fffu + ((u >> 16) & 1u)) >> 16);
}
__device__ __forceinline__ float b2f(unsigned short s) {
    return __uint_as_float(((unsigned int)s) << 16);
}

#define FMA4(P, A, Q)                                        \
    P = fmaf((A).x, (Q).x, P); P = fmaf((A).y, (Q).y, P);    \
    P = fmaf((A).z, (Q).z, P); P = fmaf((A).w, (Q).w, P);

// ---------------------------------------------------------------------------
// Kernel A: G[m][0:512] = W_ih @ x[m];  S[m] = W_self@x[m]+b_self
// 16 rows/block, 128 thr, 5 cols/thread.
// ---------------------------------------------------------------------------
__global__ __launch_bounds__(128) void ka(const float* __restrict__ x,
        const float* __restrict__ W_ih, const float* __restrict__ W_self,
        const float* __restrict__ b_self, float* __restrict__ G,
        float* __restrict__ S)
{
    __shared__ float xs[16 * DINx];
    const int m0 = blockIdx.x * 16;
    {
        const float4* src = (const float4*)(x + (size_t)m0 * DINx);
        float4* dst = (float4*)xs;
        #pragma unroll
        for (int i = 0; i < 4; ++i)
            dst[threadIdx.x + 128 * i] = src[threadIdx.x + 128 * i];
    }
    __syncthreads();

    const int t = threadIdx.x;
    const float4* wp[5];
    #pragma unroll
    for (int c = 0; c < 5; ++c) {
        const int o = t + 128 * c;
        wp[c] = (const float4*)((o < G4x) ? (W_ih + (size_t)o * DINx)
                                          : (W_self + (size_t)(o - G4x) * DINx));
    }
    float acc[16][5];
    #pragma unroll
    for (int n = 0; n < 16; ++n)
        #pragma unroll
        for (int c = 0; c < 5; ++c) acc[n][c] = 0.f;

    #pragma unroll 2
    for (int k4 = 0; k4 < 32; ++k4) {
        float4 wv[5];
        #pragma unroll
        for (int c = 0; c < 5; ++c) wv[c] = wp[c][k4];
        #pragma unroll
        for (int n = 0; n < 16; ++n) {
            const float4 xv = ((const float4*)(xs + n * DINx))[k4];
            #pragma unroll
            for (int c = 0; c < 5; ++c) { FMA4(acc[n][c], xv, wv[c]); }
        }
    }
    const float bs = b_self[t];
    #pragma unroll
    for (int n = 0; n < 16; ++n) {
        const size_t m = (size_t)(m0 + n);
        #pragma unroll
        for (int c = 0; c < 4; ++c)
            G[m * G4x + t + 128 * c] = acc[n][c];
        S[m * Hx + t] = acc[n][4] + bs;
    }
}

// ---------------------------------------------------------------------------
// Kernel W: split W_hh into bf16 hi + residual lo, packed into per-wave
// contiguous MFMA fragments (1KB chunks, lane-linear 16B/lane).
// pidx: (gdim,kcol) -> ((dg16*4+kt)*64 + quad*16 + r16)*8 + e.
// Also bsum = b_ih + b_hh.
// ---------------------------------------------------------------------------
__global__ __launch_bounds__(256) void kw(const float* __restrict__ W_hh,
        const float* __restrict__ b_ih, const float* __restrict__ b_hh,
        unsigned short* __restrict__ WHp, unsigned short* __restrict__ WLp,
        float* __restrict__ bsum)
{
    const int i = blockIdx.x * 256 + threadIdx.x;
    if (i < G4x * Hx) {
        const int gdim = i >> 7, kcol = i & 127;
        const float w = W_hh[i];
        const unsigned short hi = rne16(w);
        const unsigned short lo = rne16(w - b2f(hi));
        const int dg16 = gdim >> 4, r16 = gdim & 15;
        const int kt = kcol >> 5, quad = (kcol >> 3) & 3, e = kcol & 7;
        const int pidx = (((dg16 * 4 + kt) * 64) + quad * 16 + r16) * 8 + e;
        WHp[pidx] = hi;
        WLp[pidx] = lo;
    }
    if (i < G4x) bsum[i] = b_ih[i] + b_hh[i];
}

// ---------------------------------------------------------------------------
// Kernel B: LSTM recurrence, MFMA D = h · W_slice^T (round-4 orientation:
// A = h from LDS, B = packed W from L2 — same packed fragments by symmetry).
// 256 thr (4 waves), 32 seqs/block. Wave v owns H-dims v*32..+32 of all 4
// gates. Thread (row16=dim, quad=seq-group) -> gather reads are 64B
// contiguous per row across 16 lanes (coalesced, L3-friendly).
// acc init = wk*gather + bias BEFORE the MFMA chain (short live ranges).
// h in LDS bf16 hi/lo, 16B-granule XOR swizzle; hsF f32 aliased for epilogue.
// ---------------------------------------------------------------------------
__global__ __launch_bounds__(256, 3) void kb(const float* __restrict__ G,
        const float* __restrict__ S, const unsigned short* __restrict__ WHp,
        const unsigned short* __restrict__ WLp, const float* __restrict__ bsum,
        const int* __restrict__ nidx, const float* __restrict__ nw,
        const float* __restrict__ W_comb, const float* __restrict__ b_comb,
        float* __restrict__ out)
{
    // smem: [0,8192) hsHI u16[32][128]; [8192,16384) hsLO;
    //       hsF f32[32][136] ALIASES [0,17408) (used only after last step);
    //       [17408,+2048) gofs; [+2048) wts. total 21504 B.
    __shared__ __align__(16) char smem[21504];
    unsigned short* hsHI = (unsigned short*)smem;
    unsigned short* hsLO = (unsigned short*)(smem + 8192);
    float*          hsF  = (float*)smem;
    int*            gofs = (int*)(smem + 17408);
    float*          wts  = (float*)(smem + 17408 + 2048);

    const int tid   = threadIdx.x;
    const int lane  = tid & 63;
    const int v     = tid >> 6;         // wave 0..3
    const int row16 = lane & 15;        // H-dim within 16 (B col / D col / A row=seq for LDS reads)
    const int quad  = lane >> 4;        // 0..3
    const int kk    = row16 & 7;        // swizzle key for A reads (= seq&7 of read row)
    const int dimb  = v * 32;
    const int m0    = blockIdx.x * 32;

    for (int i = tid; i < 512; i += 256) {
        const int s = i & 31, kstep = i >> 5;
        const int m = m0 + s;
        const int bb = m / Nx;
        const int nn = m - bb * Nx;
        gofs[kstep * 32 + s] = (bb * Nx + nidx[nn * Kx + kstep]) * G4x;
        wts [kstep * 32 + s] = nw[nn * Kx + kstep];
    }
    float bsv[4][2];
    #pragma unroll
    for (int g = 0; g < 4; ++g)
        #pragma unroll
        for (int b2 = 0; b2 < 2; ++b2)
            bsv[g][b2] = bsum[g * 128 + dimb + (b2 << 4) + row16];

    float cst[2][2][4];   // [mt][b2][j]
    #pragma unroll
    for (int mt = 0; mt < 2; ++mt)
        #pragma unroll
        for (int b2 = 0; b2 < 2; ++b2)
            #pragma unroll
            for (int j = 0; j < 4; ++j) cst[mt][b2][j] = 0.f;

    __syncthreads();

    #pragma unroll 1
    for (int k = 0; k < Kx; ++k) {
        // ---- per-seq weights + 32-bit gather offsets (seq = mt*16+quad*4+j)
        float wkv[2][4];
        int   goff[2][4];
        #pragma unroll
        for (int mt = 0; mt < 2; ++mt)
            #pragma unroll
            for (int j = 0; j < 4; ++j) {
                const int seq = mt * 16 + quad * 4 + j;
                wkv[mt][j]  = wts[k * 32 + seq];
                goff[mt][j] = gofs[k * 32 + seq] + dimb + row16;
            }

        // ---- acc = wk * gathered_G + bias  (MFMA accumulates on top) ----
        f32x4 acc[2][4][2];   // [mt][g][b2], j packed in the f32x4
        #pragma unroll
        for (int mt = 0; mt < 2; ++mt)
            #pragma unroll
            for (int g = 0; g < 4; ++g)
                #pragma unroll
                for (int b2 = 0; b2 < 2; ++b2)
                    #pragma unroll
                    for (int j = 0; j < 4; ++j)
                        acc[mt][g][b2][j] = fmaf(wkv[mt][j],
                            G[(size_t)(goff[mt][j] + (g << 7) + (b2 << 4))],
                            bsv[g][b2]);

        if (k) {  // h == 0 at k == 0
            #pragma unroll
            for (int kt = 0; kt < 4; ++kt) {
                const int rsw = ((kt << 2) + quad) ^ kk;
                sh8 ahi[2], alo[2];
                #pragma unroll
                for (int mt = 0; mt < 2; ++mt) {
                    const int ro = (mt * 16 + row16) * 16 + rsw;  // sh8 units
                    ahi[mt] = ((const sh8*)hsHI)[ro];
                    alo[mt] = ((const sh8*)hsLO)[ro];
                }
                #pragma unroll
                for (int g = 0; g < 4; ++g)
                    #pragma unroll
                    for (int b2 = 0; b2 < 2; ++b2) {
                        const int wi = ((g * 8 + v * 2 + b2) * 4 + kt) * 64 + lane;
                        const sh8 wh = ((const sh8*)WHp)[wi];
                        const sh8 wl = ((const sh8*)WLp)[wi];
                        #pragma unroll
                        for (int mt = 0; mt < 2; ++mt) {
                            acc[mt][g][b2] = __builtin_amdgcn_mfma_f32_16x16x32_bf16(
                                ahi[mt], wh, acc[mt][g][b2], 0, 0, 0);
                            acc[mt][g][b2] = __builtin_amdgcn_mfma_f32_16x16x32_bf16(
                                alo[mt], wh, acc[mt][g][b2], 0, 0, 0);
                            acc[mt][g][b2] = __builtin_amdgcn_mfma_f32_16x16x32_bf16(
                                ahi[mt], wl, acc[mt][g][b2], 0, 0, 0);
                        }
                    }
            }
        }

        // ---- activations: i,f,g,o -> c,h (registers only) ----
        float hval[2][2][4];   // [mt][b2][j]
        #pragma unroll
        for (int mt = 0; mt < 2; ++mt)
            #pragma unroll
            for (int b2 = 0; b2 < 2; ++b2)
                #pragma unroll
                for (int j = 0; j < 4; ++j) {
                    const float ig = sigf(acc[mt][0][b2][j]);
                    const float fg = sigf(acc[mt][1][b2][j]);
                    const float gg = tanf_(acc[mt][2][b2][j]);
                    const float og = sigf(acc[mt][3][b2][j]);
                    const float cc = fg * cst[mt][b2][j] + ig * gg;
                    cst[mt][b2][j] = cc;
                    hval[mt][b2][j] = og * tanf_(cc);
                }

        __syncthreads();  // all hs reads of this step done before overwrite

        if (k < Kx - 1) {
            #pragma unroll
            for (int mt = 0; mt < 2; ++mt)
                #pragma unroll
                for (int b2 = 0; b2 < 2; ++b2)
                    #pragma unroll
                    for (int j = 0; j < 4; ++j) {
                        const int seq = mt * 16 + quad * 4 + j;
                        const int dim = dimb + (b2 << 4) + row16;
                        const int idx = (seq << 7) +
                                        ((((dim >> 3) ^ (seq & 7))) << 3) + (dim & 7);
                        const float f = hval[mt][b2][j];
                        const unsigned short hi = rne16(f);
                        hsHI[idx] = hi;
                        hsLO[idx] = rne16(f - b2f(hi));
                    }
        } else {  // final step: park h as f32 for the epilogue (aliases hs)
            #pragma unroll
            for (int mt = 0; mt < 2; ++mt)
                #pragma unroll
                for (int b2 = 0; b2 < 2; ++b2)
                    #pragma unroll
                    for (int j = 0; j < 4; ++j) {
                        const int seq = mt * 16 + quad * 4 + j;
                        const int dim = dimb + (b2 << 4) + row16;
                        hsF[seq * 136 + dim] = hval[mt][b2][j];
                    }
        }
        __syncthreads();  // writes visible before next step's reads
    }

    // ---- epilogue: out = relu([S, h] @ W_comb^T + b_comb) ----
    const int dg = tid & 31;
    const int sg = tid >> 5;  // 0..7 -> seqs sg*4..+4
    float ac[4][4];
    #pragma unroll
    for (int i = 0; i < 4; ++i)
        #pragma unroll
        for (int j = 0; j < 4; ++j) ac[i][j] = 0.f;

    const float4* S4 = (const float4*)S;
    const float4* W4 = (const float4*)W_comb;
    #pragma unroll 4
    for (int d4 = 0; d4 < 32; ++d4) {
        float4 sv[4], wv[4];
        #pragma unroll
        for (int i = 0; i < 4; ++i)
            sv[i] = S4[(size_t)(m0 + sg * 4 + i) * 32 + d4];
        #pragma unroll
        for (int j = 0; j < 4; ++j) wv[j] = W4[(dg * 4 + j) * 64 + d4];
        #pragma unroll
        for (int i = 0; i < 4; ++i) {
            #pragma unroll
            for (int j = 0; j < 4; ++j) { FMA4(ac[i][j], sv[i], wv[j]); }
        }
    }
    #pragma unroll 4
    for (int d4 = 0; d4 < 32; ++d4) {
        float4 hvv[4], wv[4];
        #pragma unroll
        for (int i = 0; i < 4; ++i)
            hvv[i] = *(const float4*)(hsF + (sg * 4 + i) * 136 + d4 * 4);
        #pragma unroll
        for (int j = 0; j < 4; ++j) wv[j] = W4[(dg * 4 + j) * 64 + 32 + d4];
        #pragma unroll
        for (int i = 0; i < 4; ++i) {
            #pragma unroll
            for (int j = 0; j < 4; ++j) { FMA4(ac[i][j], hvv[i], wv[j]); }
        }
    }
    const float4 bc = ((const float4*)b_comb)[dg];
    #pragma unroll
    for (int i = 0; i < 4; ++i) {
        float4 o4;
        o4.x = fmaxf(ac[i][0] + bc.x, 0.f);
        o4.y = fmaxf(ac[i][1] + bc.y, 0.f);
        o4.z = fmaxf(ac[i][2] + bc.z, 0.f);
        o4.w = fmaxf(ac[i][3] + bc.w, 0.f);
        *(float4*)(out + (size_t)(m0 + sg * 4 + i) * 128 + dg * 4) = o4;
    }
}

extern "C" void kernel_launch(void* const* d_in, const int* in_sizes, int n_in,
                              void* d_out, int out_size, void* d_ws, size_t ws_size,
                              hipStream_t stream)
{
    const float* x      = (const float*)d_in[0];
    const int*   nidx   = (const int*)  d_in[1];
    const float* nw     = (const float*)d_in[2];
    const float* W_ih   = (const float*)d_in[3];
    const float* W_hh   = (const float*)d_in[4];
    const float* b_ih   = (const float*)d_in[5];
    const float* b_hh   = (const float*)d_in[6];
    const float* W_self = (const float*)d_in[7];
    const float* b_self = (const float*)d_in[8];
    const float* W_comb = (const float*)d_in[9];
    const float* b_comb = (const float*)d_in[10];
    float* out = (float*)d_out;

    float* G = (float*)d_ws;                         // 40000*512 f32 = 81.92 MB
    float* S = G + (size_t)Mx * G4x;                 // 40000*128 f32 = 20.48 MB
    unsigned short* WHp = (unsigned short*)(S + (size_t)Mx * Hx);  // 128 KB
    unsigned short* WLp = WHp + (size_t)G4x * Hx;                  // 128 KB
    float* bsum = (float*)(WLp + (size_t)G4x * Hx);                // 2 KB

    kw<<<(G4x * Hx + 255) / 256, 256, 0, stream>>>(W_hh, b_ih, b_hh, WHp, WLp, bsum);
    ka<<<Mx / 16, 128, 0, stream>>>(x, W_ih, W_self, b_self, G, S);
    kb<<<Mx / 32, 256, 0, stream>>>(G, S, WHp, WLp, bsum, nidx, nw,
                                    W_comb, b_comb, out);
}